// Round 1
// baseline (494.427 us; speedup 1.0000x reference)
//
#include <hip/hip_runtime.h>

#define T_TOK 2048
#define HID   1024
#define FFN   2048
#define NEXP  8

typedef __attribute__((ext_vector_type(8))) short bf16x8;
typedef __attribute__((ext_vector_type(4))) float f32x4;

__device__ __forceinline__ short f2bf(float f) {
    unsigned u = __builtin_bit_cast(unsigned, f);
    u = (u + 0x7fffu + ((u >> 16) & 1u)) >> 16;
    return (short)u;
}

__device__ __forceinline__ float gelu_exact(float x) {
    return 0.5f * x * (1.0f + erff(x * 0.70710678118654752f));
}

// ---------------- bucket tokens by expert ----------------
__global__ void bucket_kernel(const int* __restrict__ idx,
                              int* __restrict__ offs, int* __restrict__ cnts,
                              int* __restrict__ tokl) {
    __shared__ int c[NEXP], cur[NEXP], o[NEXP];
    int tid = threadIdx.x;
    if (tid < NEXP) { c[tid] = 0; cur[tid] = 0; }
    __syncthreads();
    for (int t = tid; t < T_TOK; t += 256) atomicAdd(&c[idx[t]], 1);
    __syncthreads();
    if (tid == 0) {
        int s = 0;
        for (int e = 0; e < NEXP; e++) { o[e] = s; s += c[e]; }
    }
    __syncthreads();
    if (tid < NEXP) { offs[tid] = o[tid]; cnts[tid] = c[tid]; }
    for (int t = tid; t < T_TOK; t += 256) {
        int e = idx[t];
        int p = o[e] + atomicAdd(&cur[e], 1);
        tokl[p] = t;
    }
}

// ---------------- GEMM1: h = gelu(x_gathered @ W1[e] + b1[e]) ----------------
// grid: (FFN/128, 16, NEXP), block 256
__global__ __launch_bounds__(256) void gemm1_kernel(
        const float* __restrict__ x, const float* __restrict__ W1,
        const float* __restrict__ b1,
        const int* __restrict__ offs, const int* __restrict__ cnts,
        const int* __restrict__ tokl, short* __restrict__ hg) {
    int e = blockIdx.z;
    int count = cnts[e];
    int t0 = blockIdx.y * 128;
    if (t0 >= count) return;
    int off = offs[e];
    int n0 = blockIdx.x * 128;

    __shared__ short As[128][40];   // A[m][k] bf16, pad->stride 40 (2-way bank = free)
    __shared__ short Bs[128][40];   // B^T: Bs[n][k]
    __shared__ int   stok[128];

    int tid = threadIdx.x;
    if (tid < 128) {
        int p = t0 + tid;
        stok[tid] = tokl[off + (p < count ? p : 0)];
    }
    __syncthreads();

    const float* W1e = W1 + (size_t)e * HID * FFN;

    f32x4 acc[4][4];
#pragma unroll
    for (int i = 0; i < 4; i++)
#pragma unroll
        for (int j = 0; j < 4; j++) acc[i][j] = (f32x4){0.f, 0.f, 0.f, 0.f};

    int wave = tid >> 6, lane = tid & 63;
    int wm = (wave >> 1) * 64, wn = (wave & 1) * 64;
    int l15 = lane & 15, quad = lane >> 4;

    for (int k0 = 0; k0 < HID; k0 += 32) {
        // stage A: 128 rows x 32 cols (f32 -> bf16)
#pragma unroll
        for (int i = 0; i < 4; i++) {
            int c = tid + i * 256;          // 0..1023
            int r = c >> 3, cc = (c & 7) * 4;
            const float4 v = *(const float4*)(x + (size_t)stok[r] * HID + k0 + cc);
            *(short4*)(&As[r][cc]) = make_short4(f2bf(v.x), f2bf(v.y), f2bf(v.z), f2bf(v.w));
        }
        // stage B (transpose): 32 k-rows x 128 n-cols
#pragma unroll
        for (int i = 0; i < 4; i++) {
            int c = tid + i * 256;
            int k = c >> 5, nn = (c & 31) * 4;
            const float4 v = *(const float4*)(W1e + (size_t)(k0 + k) * FFN + n0 + nn);
            Bs[nn + 0][k] = f2bf(v.x);
            Bs[nn + 1][k] = f2bf(v.y);
            Bs[nn + 2][k] = f2bf(v.z);
            Bs[nn + 3][k] = f2bf(v.w);
        }
        __syncthreads();

        bf16x8 a[4], b[4];
#pragma unroll
        for (int mt = 0; mt < 4; mt++)
            a[mt] = *(const bf16x8*)(&As[wm + mt * 16 + l15][quad * 8]);
#pragma unroll
        for (int nt = 0; nt < 4; nt++)
            b[nt] = *(const bf16x8*)(&Bs[wn + nt * 16 + l15][quad * 8]);
#pragma unroll
        for (int mt = 0; mt < 4; mt++)
#pragma unroll
            for (int nt = 0; nt < 4; nt++)
                acc[mt][nt] = __builtin_amdgcn_mfma_f32_16x16x32_bf16(
                    a[mt], b[nt], acc[mt][nt], 0, 0, 0);
        __syncthreads();
    }

    // epilogue: +b1, exact GELU, store bf16 to gathered h
#pragma unroll
    for (int mt = 0; mt < 4; mt++) {
        int rbase = wm + mt * 16 + quad * 4;
#pragma unroll
        for (int nt = 0; nt < 4; nt++) {
            int coln = n0 + wn + nt * 16 + l15;
            float bb = b1[e * FFN + coln];
#pragma unroll
            for (int r = 0; r < 4; r++) {
                int p = t0 + rbase + r;
                if (p < count) {
                    float hv = gelu_exact(acc[mt][nt][r] + bb);
                    hg[(size_t)(off + p) * FFN + coln] = f2bf(hv);
                }
            }
        }
    }
}

// ---------------- GEMM2: out[token] = h_gathered @ W2[e] + b2[e] ----------------
// grid: (HID/128, 16, NEXP), block 256
__global__ __launch_bounds__(256) void gemm2_kernel(
        const short* __restrict__ hg, const float* __restrict__ W2,
        const float* __restrict__ b2,
        const int* __restrict__ offs, const int* __restrict__ cnts,
        const int* __restrict__ tokl, float* __restrict__ out) {
    int e = blockIdx.z;
    int count = cnts[e];
    int t0 = blockIdx.y * 128;
    if (t0 >= count) return;
    int off = offs[e];
    int n0 = blockIdx.x * 128;

    __shared__ short As[128][40];
    __shared__ short Bs[128][40];

    int tid = threadIdx.x;
    const float* W2e = W2 + (size_t)e * FFN * HID;

    f32x4 acc[4][4];
#pragma unroll
    for (int i = 0; i < 4; i++)
#pragma unroll
        for (int j = 0; j < 4; j++) acc[i][j] = (f32x4){0.f, 0.f, 0.f, 0.f};

    int wave = tid >> 6, lane = tid & 63;
    int wm = (wave >> 1) * 64, wn = (wave & 1) * 64;
    int l15 = lane & 15, quad = lane >> 4;

    for (int k0 = 0; k0 < FFN; k0 += 32) {
        // stage A: gathered h rows (already bf16), 16B chunks
#pragma unroll
        for (int i = 0; i < 2; i++) {
            int c = tid + i * 256;          // 0..511
            int r = c >> 2, c8 = (c & 3) * 8;
            int grow = off + t0 + r;
            if (grow > T_TOK - 1) grow = T_TOK - 1;   // pad rows: clamp (discarded later)
            *(bf16x8*)(&As[r][c8]) =
                *(const bf16x8*)(hg + (size_t)grow * FFN + k0 + c8);
        }
        // stage B (transpose): 32 k-rows x 128 n-cols of W2
#pragma unroll
        for (int i = 0; i < 4; i++) {
            int c = tid + i * 256;
            int k = c >> 5, nn = (c & 31) * 4;
            const float4 v = *(const float4*)(W2e + (size_t)(k0 + k) * HID + n0 + nn);
            Bs[nn + 0][k] = f2bf(v.x);
            Bs[nn + 1][k] = f2bf(v.y);
            Bs[nn + 2][k] = f2bf(v.z);
            Bs[nn + 3][k] = f2bf(v.w);
        }
        __syncthreads();

        bf16x8 a[4], b[4];
#pragma unroll
        for (int mt = 0; mt < 4; mt++)
            a[mt] = *(const bf16x8*)(&As[wm + mt * 16 + l15][quad * 8]);
#pragma unroll
        for (int nt = 0; nt < 4; nt++)
            b[nt] = *(const bf16x8*)(&Bs[wn + nt * 16 + l15][quad * 8]);
#pragma unroll
        for (int mt = 0; mt < 4; mt++)
#pragma unroll
            for (int nt = 0; nt < 4; nt++)
                acc[mt][nt] = __builtin_amdgcn_mfma_f32_16x16x32_bf16(
                    a[mt], b[nt], acc[mt][nt], 0, 0, 0);
        __syncthreads();
    }

    // epilogue: +b2, scatter to out[token]
#pragma unroll
    for (int mt = 0; mt < 4; mt++) {
        int rbase = wm + mt * 16 + quad * 4;
#pragma unroll
        for (int nt = 0; nt < 4; nt++) {
            int coln = n0 + wn + nt * 16 + l15;
            float bb = b2[e * HID + coln];
#pragma unroll
            for (int r = 0; r < 4; r++) {
                int p = t0 + rbase + r;
                if (p < count) {
                    int tok = tokl[off + p];
                    out[(size_t)tok * HID + coln] = acc[mt][nt][r] + bb;
                }
            }
        }
    }
}

extern "C" void kernel_launch(void* const* d_in, const int* in_sizes, int n_in,
                              void* d_out, int out_size, void* d_ws, size_t ws_size,
                              hipStream_t stream) {
    const float* x   = (const float*)d_in[0];
    const int*   idx = (const int*)d_in[1];
    const float* W1  = (const float*)d_in[2];
    const float* b1  = (const float*)d_in[3];
    const float* W2  = (const float*)d_in[4];
    const float* b2  = (const float*)d_in[5];
    float* out = (float*)d_out;

    // workspace layout
    int*   offs = (int*)d_ws;          // [8]
    int*   cnts = offs + 8;            // [8]
    int*   tokl = offs + 16;           // [2048]
    short* hg   = (short*)((char*)d_ws + 16384);  // [2048][FFN] bf16 = 8 MB

    bucket_kernel<<<1, 256, 0, stream>>>(idx, offs, cnts, tokl);
    gemm1_kernel<<<dim3(FFN / 128, 16, NEXP), 256, 0, stream>>>(
        x, W1, b1, offs, cnts, tokl, hg);
    gemm2_kernel<<<dim3(HID / 128, 16, NEXP), 256, 0, stream>>>(
        hg, W2, b2, offs, cnts, tokl, out);
}

// Round 2
// 255.165 us; speedup vs baseline: 1.9377x; 1.9377x over previous
//
#include <hip/hip_runtime.h>

#define T_TOK 2048
#define HID   1024
#define FFN   2048
#define NEXP  8

typedef __attribute__((ext_vector_type(8))) short bf16x8;
typedef __attribute__((ext_vector_type(4))) float f32x4;

__device__ __forceinline__ short f2bf(float f) {
    unsigned u = __builtin_bit_cast(unsigned, f);
    u = (u + 0x7fffu + ((u >> 16) & 1u)) >> 16;
    return (short)u;
}

__device__ __forceinline__ float gelu_exact(float x) {
    return 0.5f * x * (1.0f + erff(x * 0.70710678118654752f));
}

// ---------------- bucket tokens by expert ----------------
__global__ void bucket_kernel(const int* __restrict__ idx,
                              int* __restrict__ offs, int* __restrict__ cnts,
                              int* __restrict__ tokl) {
    __shared__ int c[NEXP], cur[NEXP], o[NEXP];
    int tid = threadIdx.x;
    if (tid < NEXP) { c[tid] = 0; cur[tid] = 0; }
    __syncthreads();
    for (int t = tid; t < T_TOK; t += 256) atomicAdd(&c[idx[t]], 1);
    __syncthreads();
    if (tid == 0) {
        int s = 0;
        for (int e = 0; e < NEXP; e++) { o[e] = s; s += c[e]; }
    }
    __syncthreads();
    if (tid < NEXP) { offs[tid] = o[tid]; cnts[tid] = c[tid]; }
    for (int t = tid; t < T_TOK; t += 256) {
        int e = idx[t];
        int p = o[e] + atomicAdd(&cur[e], 1);
        tokl[p] = t;
    }
}

// ---------------- x f32 -> bf16 ----------------
__global__ __launch_bounds__(256) void xcvt_kernel(const float* __restrict__ x,
                                                   short* __restrict__ xb) {
    int i = (blockIdx.x * 256 + threadIdx.x) * 8;
    float4 v0 = *(const float4*)(x + i);
    float4 v1 = *(const float4*)(x + i + 4);
    bf16x8 r = {f2bf(v0.x), f2bf(v0.y), f2bf(v0.z), f2bf(v0.w),
                f2bf(v1.x), f2bf(v1.y), f2bf(v1.z), f2bf(v1.w)};
    *(bf16x8*)(xb + i) = r;
}

// ---------------- W [E][K][N] f32 -> WT [E][N][K] bf16 ----------------
// grid (N/64, K/64, E), block 256. XOR chunk-swizzle in LDS to break
// transpose scatter conflicts.
__global__ __launch_bounds__(256) void wtrans_kernel(const float* __restrict__ W,
                                                     short* __restrict__ WT,
                                                     int K, int N) {
    int e = blockIdx.z;
    int n0 = blockIdx.x * 64, k0 = blockIdx.y * 64;
    const float* We = W + (size_t)e * K * N;
    short* WTe = WT + (size_t)e * N * K;
    __shared__ short Ts[64][72];
    int tid = threadIdx.x;
#pragma unroll
    for (int i = 0; i < 4; i++) {
        int c = tid + i * 256;               // [0,1024)
        int k = c >> 4, n4 = (c & 15) * 4;
        float4 v = *(const float4*)(We + (size_t)(k0 + k) * N + n0 + n4);
        short s0 = f2bf(v.x), s1 = f2bf(v.y), s2 = f2bf(v.z), s3 = f2bf(v.w);
        int ck = k >> 3, kj = k & 7;
        Ts[n4 + 0][((ck ^ (((n4 + 0) >> 3) & 7)) << 3) + kj] = s0;
        Ts[n4 + 1][((ck ^ (((n4 + 1) >> 3) & 7)) << 3) + kj] = s1;
        Ts[n4 + 2][((ck ^ (((n4 + 2) >> 3) & 7)) << 3) + kj] = s2;
        Ts[n4 + 3][((ck ^ (((n4 + 3) >> 3) & 7)) << 3) + kj] = s3;
    }
    __syncthreads();
#pragma unroll
    for (int i = 0; i < 2; i++) {
        int c = tid + i * 256;               // [0,512)
        int n = c >> 3, ck = c & 7;
        bf16x8 v = *(const bf16x8*)&Ts[n][(ck ^ ((n >> 3) & 7)) << 3];
        *(bf16x8*)(WTe + (size_t)(n0 + n) * K + k0 + ck * 8) = v;
    }
}

// ---------------- GEMM1: h = gelu(xb_gathered @ W1T^T + b1) ----------------
// all-bf16, 64x64 tile, BK=64. grid (FFN/64, T_TOK/64, NEXP), block 256.
__global__ __launch_bounds__(256) void gemm1_kernel(
        const short* __restrict__ xb, const short* __restrict__ W1T,
        const float* __restrict__ b1,
        const int* __restrict__ offs, const int* __restrict__ cnts,
        const int* __restrict__ tokl, short* __restrict__ hg) {
    int e = blockIdx.z;
    int count = cnts[e];
    int t0 = blockIdx.y * 64;
    if (t0 >= count) return;
    int off = offs[e];
    int n0 = blockIdx.x * 64;

    __shared__ short As[64][72];
    __shared__ short Bs[64][72];
    __shared__ int stok[64];

    int tid = threadIdx.x;
    if (tid < 64) {
        int p = t0 + tid;
        stok[tid] = tokl[off + (p < count ? p : count - 1)];
    }
    __syncthreads();

    const short* Be = W1T + (size_t)e * FFN * HID + (size_t)n0 * HID;

    f32x4 acc[2][2];
#pragma unroll
    for (int i = 0; i < 2; i++)
#pragma unroll
        for (int j = 0; j < 2; j++) acc[i][j] = (f32x4){0.f, 0.f, 0.f, 0.f};

    int w = tid >> 6, lane = tid & 63, l15 = lane & 15, quad = lane >> 4;
    int wm = (w >> 1) * 32, wn = (w & 1) * 32;
    int sr0 = tid >> 3, sc = (tid & 7) * 8;   // staging coords (2 chunks/thread)

    for (int k0 = 0; k0 < HID; k0 += 64) {
#pragma unroll
        for (int i = 0; i < 2; i++) {
            int r = sr0 + i * 32;
            *(bf16x8*)&As[r][sc] = *(const bf16x8*)(xb + (size_t)stok[r] * HID + k0 + sc);
            *(bf16x8*)&Bs[r][sc] = *(const bf16x8*)(Be + (size_t)r * HID + k0 + sc);
        }
        __syncthreads();
#pragma unroll
        for (int kk = 0; kk < 2; kk++) {
            int kc = kk * 32 + quad * 8;
            bf16x8 a0 = *(const bf16x8*)&As[wm + l15][kc];
            bf16x8 a1 = *(const bf16x8*)&As[wm + 16 + l15][kc];
            bf16x8 bb0 = *(const bf16x8*)&Bs[wn + l15][kc];
            bf16x8 bb1 = *(const bf16x8*)&Bs[wn + 16 + l15][kc];
            acc[0][0] = __builtin_amdgcn_mfma_f32_16x16x32_bf16(a0, bb0, acc[0][0], 0, 0, 0);
            acc[0][1] = __builtin_amdgcn_mfma_f32_16x16x32_bf16(a0, bb1, acc[0][1], 0, 0, 0);
            acc[1][0] = __builtin_amdgcn_mfma_f32_16x16x32_bf16(a1, bb0, acc[1][0], 0, 0, 0);
            acc[1][1] = __builtin_amdgcn_mfma_f32_16x16x32_bf16(a1, bb1, acc[1][1], 0, 0, 0);
        }
        __syncthreads();
    }

#pragma unroll
    for (int mt = 0; mt < 2; mt++) {
        int rbase = wm + mt * 16 + quad * 4;
#pragma unroll
        for (int nt = 0; nt < 2; nt++) {
            int coln = n0 + wn + nt * 16 + l15;
            float bb = b1[e * FFN + coln];
#pragma unroll
            for (int r = 0; r < 4; r++) {
                int p = t0 + rbase + r;
                if (p < count) {
                    float hv = gelu_exact(acc[mt][nt][r] + bb);
                    hg[(size_t)(off + p) * FFN + coln] = f2bf(hv);
                }
            }
        }
    }
}

// ---------------- GEMM2: out[token] = hg_gathered @ W2T^T + b2 ----------------
// grid (HID/64, T_TOK/64, NEXP), block 256.
__global__ __launch_bounds__(256) void gemm2_kernel(
        const short* __restrict__ hg, const short* __restrict__ W2T,
        const float* __restrict__ b2,
        const int* __restrict__ offs, const int* __restrict__ cnts,
        const int* __restrict__ tokl, float* __restrict__ out) {
    int e = blockIdx.z;
    int count = cnts[e];
    int t0 = blockIdx.y * 64;
    if (t0 >= count) return;
    int off = offs[e];
    int n0 = blockIdx.x * 64;

    __shared__ short As[64][72];
    __shared__ short Bs[64][72];

    int tid = threadIdx.x;
    const short* Be = W2T + (size_t)e * HID * FFN + (size_t)n0 * FFN;

    f32x4 acc[2][2];
#pragma unroll
    for (int i = 0; i < 2; i++)
#pragma unroll
        for (int j = 0; j < 2; j++) acc[i][j] = (f32x4){0.f, 0.f, 0.f, 0.f};

    int w = tid >> 6, lane = tid & 63, l15 = lane & 15, quad = lane >> 4;
    int wm = (w >> 1) * 32, wn = (w & 1) * 32;
    int sr0 = tid >> 3, sc = (tid & 7) * 8;

    for (int k0 = 0; k0 < FFN; k0 += 64) {
#pragma unroll
        for (int i = 0; i < 2; i++) {
            int r = sr0 + i * 32;
            int p = t0 + r;
            int grow = off + (p < count ? p : count - 1);
            *(bf16x8*)&As[r][sc] = *(const bf16x8*)(hg + (size_t)grow * FFN + k0 + sc);
            *(bf16x8*)&Bs[r][sc] = *(const bf16x8*)(Be + (size_t)r * FFN + k0 + sc);
        }
        __syncthreads();
#pragma unroll
        for (int kk = 0; kk < 2; kk++) {
            int kc = kk * 32 + quad * 8;
            bf16x8 a0 = *(const bf16x8*)&As[wm + l15][kc];
            bf16x8 a1 = *(const bf16x8*)&As[wm + 16 + l15][kc];
            bf16x8 bb0 = *(const bf16x8*)&Bs[wn + l15][kc];
            bf16x8 bb1 = *(const bf16x8*)&Bs[wn + 16 + l15][kc];
            acc[0][0] = __builtin_amdgcn_mfma_f32_16x16x32_bf16(a0, bb0, acc[0][0], 0, 0, 0);
            acc[0][1] = __builtin_amdgcn_mfma_f32_16x16x32_bf16(a0, bb1, acc[0][1], 0, 0, 0);
            acc[1][0] = __builtin_amdgcn_mfma_f32_16x16x32_bf16(a1, bb0, acc[1][0], 0, 0, 0);
            acc[1][1] = __builtin_amdgcn_mfma_f32_16x16x32_bf16(a1, bb1, acc[1][1], 0, 0, 0);
        }
        __syncthreads();
    }

#pragma unroll
    for (int mt = 0; mt < 2; mt++) {
        int rbase = wm + mt * 16 + quad * 4;
#pragma unroll
        for (int nt = 0; nt < 2; nt++) {
            int coln = n0 + wn + nt * 16 + l15;
            float bb = b2[e * HID + coln];
#pragma unroll
            for (int r = 0; r < 4; r++) {
                int p = t0 + rbase + r;
                if (p < count) {
                    int tok = tokl[off + p];
                    out[(size_t)tok * HID + coln] = acc[mt][nt][r] + bb;
                }
            }
        }
    }
}

// ================= fallback path (round-1 kernels, f32 weights) =============
__global__ __launch_bounds__(256) void gemm1_fb(
        const float* __restrict__ x, const float* __restrict__ W1,
        const float* __restrict__ b1,
        const int* __restrict__ offs, const int* __restrict__ cnts,
        const int* __restrict__ tokl, short* __restrict__ hg) {
    int e = blockIdx.z;
    int count = cnts[e];
    int t0 = blockIdx.y * 128;
    if (t0 >= count) return;
    int off = offs[e];
    int n0 = blockIdx.x * 128;
    __shared__ short As[128][40];
    __shared__ short Bs[128][40];
    __shared__ int stok[128];
    int tid = threadIdx.x;
    if (tid < 128) {
        int p = t0 + tid;
        stok[tid] = tokl[off + (p < count ? p : 0)];
    }
    __syncthreads();
    const float* W1e = W1 + (size_t)e * HID * FFN;
    f32x4 acc[4][4];
#pragma unroll
    for (int i = 0; i < 4; i++)
#pragma unroll
        for (int j = 0; j < 4; j++) acc[i][j] = (f32x4){0.f, 0.f, 0.f, 0.f};
    int wave = tid >> 6, lane = tid & 63;
    int wm = (wave >> 1) * 64, wn = (wave & 1) * 64;
    int l15 = lane & 15, quad = lane >> 4;
    for (int k0 = 0; k0 < HID; k0 += 32) {
#pragma unroll
        for (int i = 0; i < 4; i++) {
            int c = tid + i * 256;
            int r = c >> 3, cc = (c & 7) * 4;
            const float4 v = *(const float4*)(x + (size_t)stok[r] * HID + k0 + cc);
            *(short4*)(&As[r][cc]) = make_short4(f2bf(v.x), f2bf(v.y), f2bf(v.z), f2bf(v.w));
        }
#pragma unroll
        for (int i = 0; i < 4; i++) {
            int c = tid + i * 256;
            int k = c >> 5, nn = (c & 31) * 4;
            const float4 v = *(const float4*)(W1e + (size_t)(k0 + k) * FFN + n0 + nn);
            Bs[nn + 0][k] = f2bf(v.x);
            Bs[nn + 1][k] = f2bf(v.y);
            Bs[nn + 2][k] = f2bf(v.z);
            Bs[nn + 3][k] = f2bf(v.w);
        }
        __syncthreads();
        bf16x8 a[4], b[4];
#pragma unroll
        for (int mt = 0; mt < 4; mt++)
            a[mt] = *(const bf16x8*)(&As[wm + mt * 16 + l15][quad * 8]);
#pragma unroll
        for (int nt = 0; nt < 4; nt++)
            b[nt] = *(const bf16x8*)(&Bs[wn + nt * 16 + l15][quad * 8]);
#pragma unroll
        for (int mt = 0; mt < 4; mt++)
#pragma unroll
            for (int nt = 0; nt < 4; nt++)
                acc[mt][nt] = __builtin_amdgcn_mfma_f32_16x16x32_bf16(
                    a[mt], b[nt], acc[mt][nt], 0, 0, 0);
        __syncthreads();
    }
#pragma unroll
    for (int mt = 0; mt < 4; mt++) {
        int rbase = wm + mt * 16 + quad * 4;
#pragma unroll
        for (int nt = 0; nt < 4; nt++) {
            int coln = n0 + wn + nt * 16 + l15;
            float bb = b1[e * FFN + coln];
#pragma unroll
            for (int r = 0; r < 4; r++) {
                int p = t0 + rbase + r;
                if (p < count) {
                    float hv = gelu_exact(acc[mt][nt][r] + bb);
                    hg[(size_t)(off + p) * FFN + coln] = f2bf(hv);
                }
            }
        }
    }
}

__global__ __launch_bounds__(256) void gemm2_fb(
        const short* __restrict__ hg, const float* __restrict__ W2,
        const float* __restrict__ b2,
        const int* __restrict__ offs, const int* __restrict__ cnts,
        const int* __restrict__ tokl, float* __restrict__ out) {
    int e = blockIdx.z;
    int count = cnts[e];
    int t0 = blockIdx.y * 128;
    if (t0 >= count) return;
    int off = offs[e];
    int n0 = blockIdx.x * 128;
    __shared__ short As[128][40];
    __shared__ short Bs[128][40];
    int tid = threadIdx.x;
    const float* W2e = W2 + (size_t)e * FFN * HID;
    f32x4 acc[4][4];
#pragma unroll
    for (int i = 0; i < 4; i++)
#pragma unroll
        for (int j = 0; j < 4; j++) acc[i][j] = (f32x4){0.f, 0.f, 0.f, 0.f};
    int wave = tid >> 6, lane = tid & 63;
    int wm = (wave >> 1) * 64, wn = (wave & 1) * 64;
    int l15 = lane & 15, quad = lane >> 4;
    for (int k0 = 0; k0 < FFN; k0 += 32) {
#pragma unroll
        for (int i = 0; i < 2; i++) {
            int c = tid + i * 256;
            int r = c >> 2, c8 = (c & 3) * 8;
            int grow = off + t0 + r;
            if (grow > T_TOK - 1) grow = T_TOK - 1;
            *(bf16x8*)(&As[r][c8]) =
                *(const bf16x8*)(hg + (size_t)grow * FFN + k0 + c8);
        }
#pragma unroll
        for (int i = 0; i < 4; i++) {
            int c = tid + i * 256;
            int k = c >> 5, nn = (c & 31) * 4;
            const float4 v = *(const float4*)(W2e + (size_t)(k0 + k) * HID + n0 + nn);
            Bs[nn + 0][k] = f2bf(v.x);
            Bs[nn + 1][k] = f2bf(v.y);
            Bs[nn + 2][k] = f2bf(v.z);
            Bs[nn + 3][k] = f2bf(v.w);
        }
        __syncthreads();
        bf16x8 a[4], b[4];
#pragma unroll
        for (int mt = 0; mt < 4; mt++)
            a[mt] = *(const bf16x8*)(&As[wm + mt * 16 + l15][quad * 8]);
#pragma unroll
        for (int nt = 0; nt < 4; nt++)
            b[nt] = *(const bf16x8*)(&Bs[wn + nt * 16 + l15][quad * 8]);
#pragma unroll
        for (int mt = 0; mt < 4; mt++)
#pragma unroll
            for (int nt = 0; nt < 4; nt++)
                acc[mt][nt] = __builtin_amdgcn_mfma_f32_16x16x32_bf16(
                    a[mt], b[nt], acc[mt][nt], 0, 0, 0);
        __syncthreads();
    }
#pragma unroll
    for (int mt = 0; mt < 4; mt++) {
        int rbase = wm + mt * 16 + quad * 4;
#pragma unroll
        for (int nt = 0; nt < 4; nt++) {
            int coln = n0 + wn + nt * 16 + l15;
            float bb = b2[e * HID + coln];
#pragma unroll
            for (int r = 0; r < 4; r++) {
                int p = t0 + rbase + r;
                if (p < count) {
                    int tok = tokl[off + p];
                    out[(size_t)tok * HID + coln] = acc[mt][nt][r] + bb;
                }
            }
        }
    }
}

extern "C" void kernel_launch(void* const* d_in, const int* in_sizes, int n_in,
                              void* d_out, int out_size, void* d_ws, size_t ws_size,
                              hipStream_t stream) {
    const float* x   = (const float*)d_in[0];
    const int*   idx = (const int*)d_in[1];
    const float* W1  = (const float*)d_in[2];
    const float* b1  = (const float*)d_in[3];
    const float* W2  = (const float*)d_in[4];
    const float* b2  = (const float*)d_in[5];
    float* out = (float*)d_out;

    const size_t META = 32768;
    const size_t XB_SZ  = (size_t)T_TOK * HID * 2;        // 4 MB
    const size_t HG_SZ  = (size_t)T_TOK * FFN * 2;        // 8 MB
    const size_t W1T_SZ = (size_t)NEXP * FFN * HID * 2;   // 32 MB
    const size_t W2T_SZ = (size_t)NEXP * HID * FFN * 2;   // 32 MB
    const size_t NEED = META + XB_SZ + HG_SZ + W1T_SZ + W2T_SZ;

    int*   offs = (int*)d_ws;
    int*   cnts = offs + 8;
    int*   tokl = offs + 16;

    bucket_kernel<<<1, 256, 0, stream>>>(idx, offs, cnts, tokl);

    if (ws_size >= NEED) {
        short* xb  = (short*)((char*)d_ws + META);
        short* hg  = (short*)((char*)d_ws + META + XB_SZ);
        short* W1T = (short*)((char*)d_ws + META + XB_SZ + HG_SZ);
        short* W2T = (short*)((char*)d_ws + META + XB_SZ + HG_SZ + W1T_SZ);

        xcvt_kernel<<<T_TOK * HID / (256 * 8), 256, 0, stream>>>(x, xb);
        wtrans_kernel<<<dim3(FFN / 64, HID / 64, NEXP), 256, 0, stream>>>(W1, W1T, HID, FFN);
        wtrans_kernel<<<dim3(HID / 64, FFN / 64, NEXP), 256, 0, stream>>>(W2, W2T, FFN, HID);

        gemm1_kernel<<<dim3(FFN / 64, T_TOK / 64, NEXP), 256, 0, stream>>>(
            xb, W1T, b1, offs, cnts, tokl, hg);
        gemm2_kernel<<<dim3(HID / 64, T_TOK / 64, NEXP), 256, 0, stream>>>(
            hg, W2T, b2, offs, cnts, tokl, out);
    } else {
        short* hg = (short*)((char*)d_ws + 16384);
        gemm1_fb<<<dim3(FFN / 128, 16, NEXP), 256, 0, stream>>>(
            x, W1, b1, offs, cnts, tokl, hg);
        gemm2_fb<<<dim3(HID / 128, 16, NEXP), 256, 0, stream>>>(
            hg, W2, b2, offs, cnts, tokl, out);
    }
}

// Round 3
// 247.864 us; speedup vs baseline: 1.9948x; 1.0295x over previous
//
#include <hip/hip_runtime.h>

#define T_TOK 2048
#define HID   1024
#define FFN   2048
#define NEXP  8

typedef __attribute__((ext_vector_type(8))) short bf16x8;
typedef __attribute__((ext_vector_type(4))) float f32x4;

__device__ __forceinline__ short f2bf(float f) {
    unsigned u = __builtin_bit_cast(unsigned, f);
    u = (u + 0x7fffu + ((u >> 16) & 1u)) >> 16;
    return (short)u;
}

__device__ __forceinline__ float gelu_exact(float x) {
    return 0.5f * x * (1.0f + erff(x * 0.70710678118654752f));
}

// Swizzled index into a 64x64-short LDS tile (row stride 64 shorts = 128 B).
// 16B chunks rotated by row: keeps b64/b128 accesses <=2-way bank aliased.
__device__ __forceinline__ int swz(int row, int k) {
    return row * 64 + ((((k >> 3) + row) & 7) << 3) + (k & 7);
}

// ---------------- bucket tokens by expert ----------------
__global__ void bucket_kernel(const int* __restrict__ idx,
                              int* __restrict__ offs, int* __restrict__ cnts,
                              int* __restrict__ tokl) {
    __shared__ int c[NEXP], cur[NEXP], o[NEXP];
    int tid = threadIdx.x;
    if (tid < NEXP) { c[tid] = 0; cur[tid] = 0; }
    __syncthreads();
    for (int t = tid; t < T_TOK; t += 256) atomicAdd(&c[idx[t]], 1);
    __syncthreads();
    if (tid == 0) {
        int s = 0;
        for (int e = 0; e < NEXP; e++) { o[e] = s; s += c[e]; }
    }
    __syncthreads();
    if (tid < NEXP) { offs[tid] = o[tid]; cnts[tid] = c[tid]; }
    for (int t = tid; t < T_TOK; t += 256) {
        int e = idx[t];
        int p = o[e] + atomicAdd(&cur[e], 1);
        tokl[p] = t;
    }
}

// ---------------- x f32 -> bf16 ----------------
__global__ __launch_bounds__(256) void xcvt_kernel(const float* __restrict__ x,
                                                   short* __restrict__ xb) {
    int i = (blockIdx.x * 256 + threadIdx.x) * 8;
    float4 v0 = *(const float4*)(x + i);
    float4 v1 = *(const float4*)(x + i + 4);
    bf16x8 r = {f2bf(v0.x), f2bf(v0.y), f2bf(v0.z), f2bf(v0.w),
                f2bf(v1.x), f2bf(v1.y), f2bf(v1.z), f2bf(v1.w)};
    *(bf16x8*)(xb + i) = r;
}

// ---------------- out[t] = b2[idx[t]] (bias init for split-K atomics) -------
__global__ __launch_bounds__(256) void initout_kernel(const int* __restrict__ idx,
                                                      const float* __restrict__ b2,
                                                      float* __restrict__ out) {
    int t = blockIdx.x;
    int e = idx[t];
    const float4* src = (const float4*)(b2 + (size_t)e * HID);
    float4* dst = (float4*)(out + (size_t)t * HID);
    dst[threadIdx.x] = src[threadIdx.x];
}

// ---------------- GEMM1: hg = gelu(xb_gathered @ W1[e] + b1[e]) -------------
// 64x64 tile, BK=64, reg-prefetch double buffer, W1 read f32 [k][n] directly.
// grid (FFN/64, T_TOK/64, NEXP), block 256.
__global__ __launch_bounds__(256) void gemm1_kernel(
        const short* __restrict__ xb, const float* __restrict__ W1,
        const float* __restrict__ b1,
        const int* __restrict__ offs, const int* __restrict__ cnts,
        const int* __restrict__ tokl, short* __restrict__ hg) {
    int e = blockIdx.z;
    int count = cnts[e];
    int t0 = blockIdx.y * 64;
    if (t0 >= count) return;
    int off = offs[e];
    int n0 = blockIdx.x * 64;

    __shared__ short As[2][64 * 64];
    __shared__ short Bs[2][64 * 64];
    __shared__ int stok[64];

    int tid = threadIdx.x;
    if (tid < 64) {
        int p = t0 + tid;
        stok[tid] = tokl[off + (p < count ? p : count - 1)];
    }
    __syncthreads();

    const float* Bsrc = W1 + (size_t)e * HID * FFN + n0;  // [k][n], stride FFN

    int w = tid >> 6, lane = tid & 63, l15 = lane & 15, quad = lane >> 4;
    int wm = (w >> 1) * 32, wn = (w & 1) * 32;
    int ar = tid >> 3, ac = (tid & 7) * 8;   // A staging: rows ar, ar+32
    int bn = tid & 63, bw = tid >> 6;        // B staging: col bn, k-group bw*16

    f32x4 acc[2][2];
#pragma unroll
    for (int i = 0; i < 2; i++)
#pragma unroll
        for (int j = 0; j < 2; j++) acc[i][j] = (f32x4){0.f, 0.f, 0.f, 0.f};

    bf16x8 pA0, pA1;
    float pB[16];

#define G1_LOADA(K0) { \
    pA0 = *(const bf16x8*)(xb + (size_t)stok[ar] * HID + (K0) + ac); \
    pA1 = *(const bf16x8*)(xb + (size_t)stok[ar + 32] * HID + (K0) + ac); }
#define G1_LOADB(K0) { \
    _Pragma("unroll") for (int i = 0; i < 4; i++) \
    _Pragma("unroll") for (int j = 0; j < 4; j++) \
        pB[i * 4 + j] = Bsrc[(size_t)((K0) + bw * 16 + i * 4 + j) * FFN + bn]; }
#define G1_STORE(BUF) { \
    *(bf16x8*)&As[BUF][swz(ar, ac)] = pA0; \
    *(bf16x8*)&As[BUF][swz(ar + 32, ac)] = pA1; \
    _Pragma("unroll") for (int i = 0; i < 4; i++) { \
        short4 s = make_short4(f2bf(pB[i*4]), f2bf(pB[i*4+1]), f2bf(pB[i*4+2]), f2bf(pB[i*4+3])); \
        *(short4*)&Bs[BUF][swz(bn, bw * 16 + i * 4)] = s; } }

    G1_LOADA(0); G1_LOADB(0);
    G1_STORE(0);
    __syncthreads();

    for (int kt = 0; kt < 16; kt++) {
        int cur = kt & 1;
        if (kt < 15) { G1_LOADA((kt + 1) * 64); G1_LOADB((kt + 1) * 64); }
#pragma unroll
        for (int kk = 0; kk < 2; kk++) {
            int kc = kk * 32 + quad * 8;
            bf16x8 a0 = *(const bf16x8*)&As[cur][swz(wm + l15, kc)];
            bf16x8 a1 = *(const bf16x8*)&As[cur][swz(wm + 16 + l15, kc)];
            bf16x8 b0 = *(const bf16x8*)&Bs[cur][swz(wn + l15, kc)];
            bf16x8 b1v = *(const bf16x8*)&Bs[cur][swz(wn + 16 + l15, kc)];
            acc[0][0] = __builtin_amdgcn_mfma_f32_16x16x32_bf16(a0, b0, acc[0][0], 0, 0, 0);
            acc[0][1] = __builtin_amdgcn_mfma_f32_16x16x32_bf16(a0, b1v, acc[0][1], 0, 0, 0);
            acc[1][0] = __builtin_amdgcn_mfma_f32_16x16x32_bf16(a1, b0, acc[1][0], 0, 0, 0);
            acc[1][1] = __builtin_amdgcn_mfma_f32_16x16x32_bf16(a1, b1v, acc[1][1], 0, 0, 0);
        }
        __syncthreads();
        if (kt < 15) G1_STORE(1 - cur);
        __syncthreads();
    }

#pragma unroll
    for (int mt = 0; mt < 2; mt++) {
        int rbase = wm + mt * 16 + quad * 4;
#pragma unroll
        for (int nt = 0; nt < 2; nt++) {
            int coln = n0 + wn + nt * 16 + l15;
            float bb = b1[e * FFN + coln];
#pragma unroll
            for (int r = 0; r < 4; r++) {
                int p = t0 + rbase + r;
                if (p < count) {
                    float hv = gelu_exact(acc[mt][nt][r] + bb);
                    hg[(size_t)(off + p) * FFN + coln] = f2bf(hv);
                }
            }
        }
    }
}

// ---------------- GEMM2: out[tok] += hg_gathered @ W2[e]  (split-K x2) ------
// grid (HID/64, T_TOK/64, NEXP*2): z -> e = z&7, ks = z>>3. block 256.
__global__ __launch_bounds__(256) void gemm2_kernel(
        const short* __restrict__ hg, const float* __restrict__ W2,
        const int* __restrict__ offs, const int* __restrict__ cnts,
        const int* __restrict__ tokl, float* __restrict__ out) {
    int e = blockIdx.z & 7;
    int ks = blockIdx.z >> 3;
    int count = cnts[e];
    int t0 = blockIdx.y * 64;
    if (t0 >= count) return;
    int off = offs[e];
    int n0 = blockIdx.x * 64;
    int kbase = ks * (FFN / 2);

    __shared__ short As[2][64 * 64];
    __shared__ short Bs[2][64 * 64];

    int tid = threadIdx.x;
    const float* Bsrc = W2 + (size_t)e * FFN * HID + n0;  // [k][n], stride HID

    int w = tid >> 6, lane = tid & 63, l15 = lane & 15, quad = lane >> 4;
    int wm = (w >> 1) * 32, wn = (w & 1) * 32;
    int ar = tid >> 3, ac = (tid & 7) * 8;
    int bn = tid & 63, bw = tid >> 6;

    int ga0 = off + (t0 + ar      < count ? t0 + ar      : count - 1);
    int ga1 = off + (t0 + ar + 32 < count ? t0 + ar + 32 : count - 1);

    f32x4 acc[2][2];
#pragma unroll
    for (int i = 0; i < 2; i++)
#pragma unroll
        for (int j = 0; j < 2; j++) acc[i][j] = (f32x4){0.f, 0.f, 0.f, 0.f};

    bf16x8 pA0, pA1;
    float pB[16];

#define G2_LOADA(K0) { \
    pA0 = *(const bf16x8*)(hg + (size_t)ga0 * FFN + (K0) + ac); \
    pA1 = *(const bf16x8*)(hg + (size_t)ga1 * FFN + (K0) + ac); }
#define G2_LOADB(K0) { \
    _Pragma("unroll") for (int i = 0; i < 4; i++) \
    _Pragma("unroll") for (int j = 0; j < 4; j++) \
        pB[i * 4 + j] = Bsrc[(size_t)((K0) + bw * 16 + i * 4 + j) * HID + bn]; }
#define G2_STORE(BUF) { \
    *(bf16x8*)&As[BUF][swz(ar, ac)] = pA0; \
    *(bf16x8*)&As[BUF][swz(ar + 32, ac)] = pA1; \
    _Pragma("unroll") for (int i = 0; i < 4; i++) { \
        short4 s = make_short4(f2bf(pB[i*4]), f2bf(pB[i*4+1]), f2bf(pB[i*4+2]), f2bf(pB[i*4+3])); \
        *(short4*)&Bs[BUF][swz(bn, bw * 16 + i * 4)] = s; } }

    G2_LOADA(kbase); G2_LOADB(kbase);
    G2_STORE(0);
    __syncthreads();

    for (int kt = 0; kt < 16; kt++) {
        int cur = kt & 1;
        if (kt < 15) { G2_LOADA(kbase + (kt + 1) * 64); G2_LOADB(kbase + (kt + 1) * 64); }
#pragma unroll
        for (int kk = 0; kk < 2; kk++) {
            int kc = kk * 32 + quad * 8;
            bf16x8 a0 = *(const bf16x8*)&As[cur][swz(wm + l15, kc)];
            bf16x8 a1 = *(const bf16x8*)&As[cur][swz(wm + 16 + l15, kc)];
            bf16x8 b0 = *(const bf16x8*)&Bs[cur][swz(wn + l15, kc)];
            bf16x8 b1v = *(const bf16x8*)&Bs[cur][swz(wn + 16 + l15, kc)];
            acc[0][0] = __builtin_amdgcn_mfma_f32_16x16x32_bf16(a0, b0, acc[0][0], 0, 0, 0);
            acc[0][1] = __builtin_amdgcn_mfma_f32_16x16x32_bf16(a0, b1v, acc[0][1], 0, 0, 0);
            acc[1][0] = __builtin_amdgcn_mfma_f32_16x16x32_bf16(a1, b0, acc[1][0], 0, 0, 0);
            acc[1][1] = __builtin_amdgcn_mfma_f32_16x16x32_bf16(a1, b1v, acc[1][1], 0, 0, 0);
        }
        __syncthreads();
        if (kt < 15) G2_STORE(1 - cur);
        __syncthreads();
    }

#pragma unroll
    for (int mt = 0; mt < 2; mt++) {
        int rbase = wm + mt * 16 + quad * 4;
#pragma unroll
        for (int nt = 0; nt < 2; nt++) {
            int coln = n0 + wn + nt * 16 + l15;
#pragma unroll
            for (int r = 0; r < 4; r++) {
                int p = t0 + rbase + r;
                if (p < count) {
                    int tok = tokl[off + p];
                    atomicAdd(out + (size_t)tok * HID + coln, acc[mt][nt][r]);
                }
            }
        }
    }
}

extern "C" void kernel_launch(void* const* d_in, const int* in_sizes, int n_in,
                              void* d_out, int out_size, void* d_ws, size_t ws_size,
                              hipStream_t stream) {
    const float* x   = (const float*)d_in[0];
    const int*   idx = (const int*)d_in[1];
    const float* W1  = (const float*)d_in[2];
    const float* b1  = (const float*)d_in[3];
    const float* W2  = (const float*)d_in[4];
    const float* b2  = (const float*)d_in[5];
    float* out = (float*)d_out;

    const size_t META = 32768;
    int*   offs = (int*)d_ws;
    int*   cnts = offs + 8;
    int*   tokl = offs + 16;
    short* xb   = (short*)((char*)d_ws + META);                      // 4 MB
    short* hg   = (short*)((char*)d_ws + META + (size_t)T_TOK * HID * 2);  // 8 MB

    bucket_kernel<<<1, 256, 0, stream>>>(idx, offs, cnts, tokl);
    xcvt_kernel<<<T_TOK * HID / (256 * 8), 256, 0, stream>>>(x, xb);
    initout_kernel<<<T_TOK, 256, 0, stream>>>(idx, b2, out);

    gemm1_kernel<<<dim3(FFN / 64, T_TOK / 64, NEXP), 256, 0, stream>>>(
        xb, W1, b1, offs, cnts, tokl, hg);
    gemm2_kernel<<<dim3(HID / 64, T_TOK / 64, NEXP * 2), 256, 0, stream>>>(
        hg, W2, offs, cnts, tokl, out);
}

// Round 4
// 245.205 us; speedup vs baseline: 2.0164x; 1.0108x over previous
//
#include <hip/hip_runtime.h>

#define T_TOK 2048
#define HID   1024
#define FFN   2048
#define NEXP  8
#define MAX_SLOTS 40

typedef __attribute__((ext_vector_type(8))) short bf16x8;
typedef __attribute__((ext_vector_type(4))) float f32x4;

__device__ __forceinline__ short f2bf(float f) {
    unsigned u = __builtin_bit_cast(unsigned, f);
    u = (u + 0x7fffu + ((u >> 16) & 1u)) >> 16;
    return (short)u;
}

__device__ __forceinline__ float gelu_exact(float x) {
    return 0.5f * x * (1.0f + erff(x * 0.70710678118654752f));
}

// Swizzled index into a 64x64-short LDS tile (row stride 64 shorts = 128 B).
// 16B chunks rotated by row: keeps b64/b128 accesses <=2-way bank aliased.
__device__ __forceinline__ int swz(int row, int k) {
    return row * 64 + ((((k >> 3) + row) & 7) << 3) + (k & 7);
}

// ---------------- bucket tokens by expert + build tile worklist -------------
__global__ void bucket_kernel(const int* __restrict__ idx,
                              int* __restrict__ offs, int* __restrict__ cnts,
                              int* __restrict__ tokl,
                              int* __restrict__ slot_e, int* __restrict__ slot_t0) {
    __shared__ int c[NEXP], cur[NEXP], o[NEXP];
    int tid = threadIdx.x;
    if (tid < NEXP) { c[tid] = 0; cur[tid] = 0; }
    __syncthreads();
    for (int t = tid; t < T_TOK; t += 256) atomicAdd(&c[idx[t]], 1);
    __syncthreads();
    if (tid == 0) {
        int s = 0;
        for (int e = 0; e < NEXP; e++) { o[e] = s; s += c[e]; }
        // tile worklist
        int ns = 0;
        for (int e = 0; e < NEXP; e++)
            for (int t0 = 0; t0 < c[e]; t0 += 64) {
                slot_e[ns] = e; slot_t0[ns] = t0; ns++;
            }
        for (; ns < MAX_SLOTS; ns++) slot_e[ns] = -1;
    }
    __syncthreads();
    if (tid < NEXP) { offs[tid] = o[tid]; cnts[tid] = c[tid]; }
    for (int t = tid; t < T_TOK; t += 256) {
        int e = idx[t];
        int p = o[e] + atomicAdd(&cur[e], 1);
        tokl[p] = t;
    }
}

// ---------------- x f32 -> bf16 ----------------
__global__ __launch_bounds__(256) void xcvt_kernel(const float* __restrict__ x,
                                                   short* __restrict__ xb) {
    int i = (blockIdx.x * 256 + threadIdx.x) * 8;
    float4 v0 = *(const float4*)(x + i);
    float4 v1 = *(const float4*)(x + i + 4);
    bf16x8 r = {f2bf(v0.x), f2bf(v0.y), f2bf(v0.z), f2bf(v0.w),
                f2bf(v1.x), f2bf(v1.y), f2bf(v1.z), f2bf(v1.w)};
    *(bf16x8*)(xb + i) = r;
}

// ---------------- out[t] = b2[idx[t]] (bias init for split-K atomics) -------
__global__ __launch_bounds__(256) void initout_kernel(const int* __restrict__ idx,
                                                      const float* __restrict__ b2,
                                                      float* __restrict__ out) {
    int t = blockIdx.x;
    int e = idx[t];
    const float4* src = (const float4*)(b2 + (size_t)e * HID);
    float4* dst = (float4*)(out + (size_t)t * HID);
    dst[threadIdx.x] = src[threadIdx.x];
}

// ---------------- GEMM1: hg = gelu(xb_gathered @ W1[e] + b1[e]) -------------
// 64x64 tile, BK=64, single-barrier double buffer, slot worklist.
// grid (FFN/64, MAX_SLOTS), block 256.
__global__ __launch_bounds__(256) void gemm1_kernel(
        const short* __restrict__ xb, const float* __restrict__ W1,
        const float* __restrict__ b1,
        const int* __restrict__ offs, const int* __restrict__ cnts,
        const int* __restrict__ tokl,
        const int* __restrict__ slot_e, const int* __restrict__ slot_t0,
        short* __restrict__ hg) {
    int s = blockIdx.y;
    int e = slot_e[s];
    if (e < 0) return;
    int t0 = slot_t0[s];
    int count = cnts[e];
    int off = offs[e];
    int n0 = blockIdx.x * 64;

    __shared__ short As[2][64 * 64];
    __shared__ short Bs[2][64 * 64];
    __shared__ int stok[64];

    int tid = threadIdx.x;
    if (tid < 64) {
        int p = t0 + tid;
        stok[tid] = tokl[off + (p < count ? p : count - 1)];
    }
    __syncthreads();

    const float* Bsrc = W1 + (size_t)e * HID * FFN + n0;  // [k][n], stride FFN

    int w = tid >> 6, lane = tid & 63, l15 = lane & 15, quad = lane >> 4;
    int wm = (w >> 1) * 32, wn = (w & 1) * 32;
    int ar = tid >> 3, ac = (tid & 7) * 8;   // A staging: rows ar, ar+32
    int bn = tid & 63, bw = tid >> 6;        // B staging: col bn, k-group bw*16

    f32x4 acc[2][2];
#pragma unroll
    for (int i = 0; i < 2; i++)
#pragma unroll
        for (int j = 0; j < 2; j++) acc[i][j] = (f32x4){0.f, 0.f, 0.f, 0.f};

    bf16x8 pA0, pA1;
    float pB[16];

#define G1_LOADA(K0) { \
    pA0 = *(const bf16x8*)(xb + (size_t)stok[ar] * HID + (K0) + ac); \
    pA1 = *(const bf16x8*)(xb + (size_t)stok[ar + 32] * HID + (K0) + ac); }
#define G1_LOADB(K0) { \
    _Pragma("unroll") for (int i = 0; i < 4; i++) \
    _Pragma("unroll") for (int j = 0; j < 4; j++) \
        pB[i * 4 + j] = Bsrc[(size_t)((K0) + bw * 16 + i * 4 + j) * FFN + bn]; }
#define G1_STORE(BUF) { \
    *(bf16x8*)&As[BUF][swz(ar, ac)] = pA0; \
    *(bf16x8*)&As[BUF][swz(ar + 32, ac)] = pA1; \
    _Pragma("unroll") for (int i = 0; i < 4; i++) { \
        short4 sv = make_short4(f2bf(pB[i*4]), f2bf(pB[i*4+1]), f2bf(pB[i*4+2]), f2bf(pB[i*4+3])); \
        *(short4*)&Bs[BUF][swz(bn, bw * 16 + i * 4)] = sv; } }

    G1_LOADA(0); G1_LOADB(0);
    G1_STORE(0);

    for (int kt = 0; kt < 16; kt++) {
        __syncthreads();
        int cur = kt & 1;
        if (kt < 15) { G1_LOADA((kt + 1) * 64); G1_LOADB((kt + 1) * 64); }
#pragma unroll
        for (int kk = 0; kk < 2; kk++) {
            int kc = kk * 32 + quad * 8;
            bf16x8 a0 = *(const bf16x8*)&As[cur][swz(wm + l15, kc)];
            bf16x8 a1 = *(const bf16x8*)&As[cur][swz(wm + 16 + l15, kc)];
            bf16x8 b0 = *(const bf16x8*)&Bs[cur][swz(wn + l15, kc)];
            bf16x8 b1v = *(const bf16x8*)&Bs[cur][swz(wn + 16 + l15, kc)];
            acc[0][0] = __builtin_amdgcn_mfma_f32_16x16x32_bf16(a0, b0, acc[0][0], 0, 0, 0);
            acc[0][1] = __builtin_amdgcn_mfma_f32_16x16x32_bf16(a0, b1v, acc[0][1], 0, 0, 0);
            acc[1][0] = __builtin_amdgcn_mfma_f32_16x16x32_bf16(a1, b0, acc[1][0], 0, 0, 0);
            acc[1][1] = __builtin_amdgcn_mfma_f32_16x16x32_bf16(a1, b1v, acc[1][1], 0, 0, 0);
        }
        if (kt < 15) G1_STORE(1 - cur);
    }

#pragma unroll
    for (int mt = 0; mt < 2; mt++) {
        int rbase = wm + mt * 16 + quad * 4;
#pragma unroll
        for (int nt = 0; nt < 2; nt++) {
            int coln = n0 + wn + nt * 16 + l15;
            float bb = b1[e * FFN + coln];
#pragma unroll
            for (int r = 0; r < 4; r++) {
                int p = t0 + rbase + r;
                if (p < count) {
                    float hv = gelu_exact(acc[mt][nt][r] + bb);
                    hg[(size_t)(off + p) * FFN + coln] = f2bf(hv);
                }
            }
        }
    }
}

// ---------------- GEMM2: out[tok] += hg_gathered @ W2[e]  (split-K x2) ------
// grid (HID/64, MAX_SLOTS, 2), block 256.
__global__ __launch_bounds__(256) void gemm2_kernel(
        const short* __restrict__ hg, const float* __restrict__ W2,
        const int* __restrict__ offs, const int* __restrict__ cnts,
        const int* __restrict__ tokl,
        const int* __restrict__ slot_e, const int* __restrict__ slot_t0,
        float* __restrict__ out) {
    int s = blockIdx.y;
    int e = slot_e[s];
    if (e < 0) return;
    int t0 = slot_t0[s];
    int ks = blockIdx.z;
    int count = cnts[e];
    int off = offs[e];
    int n0 = blockIdx.x * 64;
    int kbase = ks * (FFN / 2);

    __shared__ short As[2][64 * 64];
    __shared__ short Bs[2][64 * 64];

    int tid = threadIdx.x;
    const float* Bsrc = W2 + (size_t)e * FFN * HID + n0;  // [k][n], stride HID

    int w = tid >> 6, lane = tid & 63, l15 = lane & 15, quad = lane >> 4;
    int wm = (w >> 1) * 32, wn = (w & 1) * 32;
    int ar = tid >> 3, ac = (tid & 7) * 8;
    int bn = tid & 63, bw = tid >> 6;

    int ga0 = off + (t0 + ar      < count ? t0 + ar      : count - 1);
    int ga1 = off + (t0 + ar + 32 < count ? t0 + ar + 32 : count - 1);

    f32x4 acc[2][2];
#pragma unroll
    for (int i = 0; i < 2; i++)
#pragma unroll
        for (int j = 0; j < 2; j++) acc[i][j] = (f32x4){0.f, 0.f, 0.f, 0.f};

    bf16x8 pA0, pA1;
    float pB[16];

#define G2_LOADA(K0) { \
    pA0 = *(const bf16x8*)(hg + (size_t)ga0 * FFN + (K0) + ac); \
    pA1 = *(const bf16x8*)(hg + (size_t)ga1 * FFN + (K0) + ac); }
#define G2_LOADB(K0) { \
    _Pragma("unroll") for (int i = 0; i < 4; i++) \
    _Pragma("unroll") for (int j = 0; j < 4; j++) \
        pB[i * 4 + j] = Bsrc[(size_t)((K0) + bw * 16 + i * 4 + j) * HID + bn]; }
#define G2_STORE(BUF) { \
    *(bf16x8*)&As[BUF][swz(ar, ac)] = pA0; \
    *(bf16x8*)&As[BUF][swz(ar + 32, ac)] = pA1; \
    _Pragma("unroll") for (int i = 0; i < 4; i++) { \
        short4 sv = make_short4(f2bf(pB[i*4]), f2bf(pB[i*4+1]), f2bf(pB[i*4+2]), f2bf(pB[i*4+3])); \
        *(short4*)&Bs[BUF][swz(bn, bw * 16 + i * 4)] = sv; } }

    G2_LOADA(kbase); G2_LOADB(kbase);
    G2_STORE(0);

    for (int kt = 0; kt < 16; kt++) {
        __syncthreads();
        int cur = kt & 1;
        if (kt < 15) { G2_LOADA(kbase + (kt + 1) * 64); G2_LOADB(kbase + (kt + 1) * 64); }
#pragma unroll
        for (int kk = 0; kk < 2; kk++) {
            int kc = kk * 32 + quad * 8;
            bf16x8 a0 = *(const bf16x8*)&As[cur][swz(wm + l15, kc)];
            bf16x8 a1 = *(const bf16x8*)&As[cur][swz(wm + 16 + l15, kc)];
            bf16x8 b0 = *(const bf16x8*)&Bs[cur][swz(wn + l15, kc)];
            bf16x8 b1v = *(const bf16x8*)&Bs[cur][swz(wn + 16 + l15, kc)];
            acc[0][0] = __builtin_amdgcn_mfma_f32_16x16x32_bf16(a0, b0, acc[0][0], 0, 0, 0);
            acc[0][1] = __builtin_amdgcn_mfma_f32_16x16x32_bf16(a0, b1v, acc[0][1], 0, 0, 0);
            acc[1][0] = __builtin_amdgcn_mfma_f32_16x16x32_bf16(a1, b0, acc[1][0], 0, 0, 0);
            acc[1][1] = __builtin_amdgcn_mfma_f32_16x16x32_bf16(a1, b1v, acc[1][1], 0, 0, 0);
        }
        if (kt < 15) G2_STORE(1 - cur);
    }

#pragma unroll
    for (int mt = 0; mt < 2; mt++) {
        int rbase = wm + mt * 16 + quad * 4;
#pragma unroll
        for (int nt = 0; nt < 2; nt++) {
            int coln = n0 + wn + nt * 16 + l15;
#pragma unroll
            for (int r = 0; r < 4; r++) {
                int p = t0 + rbase + r;
                if (p < count) {
                    int tok = tokl[off + p];
                    atomicAdd(out + (size_t)tok * HID + coln, acc[mt][nt][r]);
                }
            }
        }
    }
}

extern "C" void kernel_launch(void* const* d_in, const int* in_sizes, int n_in,
                              void* d_out, int out_size, void* d_ws, size_t ws_size,
                              hipStream_t stream) {
    const float* x   = (const float*)d_in[0];
    const int*   idx = (const int*)d_in[1];
    const float* W1  = (const float*)d_in[2];
    const float* b1  = (const float*)d_in[3];
    const float* W2  = (const float*)d_in[4];
    const float* b2  = (const float*)d_in[5];
    float* out = (float*)d_out;

    const size_t META = 32768;
    int*   offs    = (int*)d_ws;
    int*   cnts    = offs + 8;
    int*   tokl    = offs + 16;         // [2048]
    int*   slot_e  = offs + 16 + T_TOK; // [MAX_SLOTS]
    int*   slot_t0 = slot_e + MAX_SLOTS;
    short* xb      = (short*)((char*)d_ws + META);                          // 4 MB
    short* hg      = (short*)((char*)d_ws + META + (size_t)T_TOK * HID * 2); // 8 MB

    bucket_kernel<<<1, 256, 0, stream>>>(idx, offs, cnts, tokl, slot_e, slot_t0);
    xcvt_kernel<<<T_TOK * HID / (256 * 8), 256, 0, stream>>>(x, xb);
    initout_kernel<<<T_TOK, 256, 0, stream>>>(idx, b2, out);

    gemm1_kernel<<<dim3(FFN / 64, MAX_SLOTS), 256, 0, stream>>>(
        xb, W1, b1, offs, cnts, tokl, slot_e, slot_t0, hg);
    gemm2_kernel<<<dim3(HID / 64, MAX_SLOTS, 2), 256, 0, stream>>>(
        hg, W2, offs, cnts, tokl, slot_e, slot_t0, out);
}